// Round 11
// baseline (302.162 us; speedup 1.0000x reference)
//
#include <hip/hip_runtime.h>
#include <hip/hip_bf16.h>
#include <math.h>

#define NB 8
#define HWN 1024
#define KVC 960

typedef short bf16x8 __attribute__((ext_vector_type(8)));
typedef float f32x4 __attribute__((ext_vector_type(4)));
typedef unsigned short ushort_t;

__device__ inline ushort_t f2bf(float f) {
    __hip_bfloat16 h = __float2bfloat16(f);
    return *reinterpret_cast<ushort_t*>(&h);
}
__device__ inline float bf2f(ushort_t u) {
    union { float f; unsigned int i; } x; x.i = ((unsigned int)u) << 16; return x.f;
}
__device__ inline void glds16(const ushort_t* src, ushort_t* dst) {
    __builtin_amdgcn_global_load_lds(
        (const __attribute__((address_space(1))) void*)src,
        (__attribute__((address_space(3))) void*)dst, 16, 0, 0);
}

// ---------------------------------------------------------------------------
// Batched f32 -> bf16 convert (no transpose). 1024 elems per block.
// ---------------------------------------------------------------------------
struct F2BTab {
    const float* src[12];
    long dstOff[12];
    int nblk[12];
    int nseg;
};

__global__ __launch_bounds__(256)
void f2b_batched(F2BTab tab, ushort_t* base)
{
    int b = blockIdx.x, s = 0;
    while (s < tab.nseg - 1 && b >= tab.nblk[s]) { b -= tab.nblk[s]; ++s; }
    float4 v = *((const float4*)tab.src[s] + (long)b * 256 + threadIdx.x);
    ushort4 o = make_ushort4(f2bf(v.x), f2bf(v.y), f2bf(v.z), f2bf(v.w));
    *((ushort4*)(base + tab.dstOff[s]) + (long)b * 256 + threadIdx.x) = o;
}

// ---------------------------------------------------------------------------
// Batched f32 -> bf16 transpose-convert: in [b][R][1024] f32 -> out [b][1024][R].
// ---------------------------------------------------------------------------
struct F2TTab {
    const float* src[5];
    long dstOff[5];
    long sIn[5], sOut[5];
    int R[5];
    int nblk[5];
    int nseg;
};

__global__ __launch_bounds__(256)
void f2bt_batched(F2TTab tab, ushort_t* base)
{
    __shared__ ushort_t tile[64][65];
    int b = blockIdx.x, s = 0;
    while (s < tab.nseg - 1 && b >= tab.nblk[s]) { b -= tab.nblk[s]; ++s; }
    const int R = tab.R[s];
    const int tpb = (R >> 6) * 16;
    const int batch = b / tpb, rem = b - batch * tpb;
    const int rtile = rem >> 4, ctile = rem & 15;
    const float* ib = tab.src[s] + (long)batch * tab.sIn[s] + (long)(rtile * 64) * 1024 + ctile * 64;
    const int t = threadIdx.x, tr = t >> 4, tc = (t & 15) * 4;
    #pragma unroll
    for (int p = 0; p < 4; ++p) {
        float4 v = *(const float4*)(ib + (long)(tr + 16 * p) * 1024 + tc);
        tile[tr + 16 * p][tc + 0] = f2bf(v.x);
        tile[tr + 16 * p][tc + 1] = f2bf(v.y);
        tile[tr + 16 * p][tc + 2] = f2bf(v.z);
        tile[tr + 16 * p][tc + 3] = f2bf(v.w);
    }
    __syncthreads();
    ushort_t* ob = base + tab.dstOff[s] + (long)batch * tab.sOut[s]
                 + (long)(ctile * 64) * R + rtile * 64;
    #pragma unroll
    for (int p = 0; p < 4; ++p) {
        ushort4 v;
        v.x = tile[tc + 0][tr + 16 * p];
        v.y = tile[tc + 1][tr + 16 * p];
        v.z = tile[tc + 2][tr + 16 * p];
        v.w = tile[tc + 3][tr + 16 * p];
        *(ushort4*)(ob + (long)(tr + 16 * p) * R + tc) = v;
    }
}

// ---------------------------------------------------------------------------
// bf16 transpose: in [b][960][1024] -> out [b][1024][960]. grid (16,15,NB).
// ---------------------------------------------------------------------------
__global__ __launch_bounds__(256)
void trb_kernel(const ushort_t* __restrict__ in, ushort_t* __restrict__ out)
{
    __shared__ ushort_t tile[64][65];
    const int r0 = blockIdx.y * 64, c0 = blockIdx.x * 64;
    const long sP = (long)KVC * HWN;
    const ushort_t* ib = in + (long)blockIdx.z * sP;
    ushort_t* ob = out + (long)blockIdx.z * sP;
    const int t = threadIdx.x, tr = t >> 4, tc = (t & 15) * 4;
    #pragma unroll
    for (int p = 0; p < 4; ++p) {
        ushort4 v = *(const ushort4*)(ib + (long)(r0 + tr + 16 * p) * 1024 + c0 + tc);
        tile[tr + 16 * p][tc + 0] = v.x;
        tile[tr + 16 * p][tc + 1] = v.y;
        tile[tr + 16 * p][tc + 2] = v.z;
        tile[tr + 16 * p][tc + 3] = v.w;
    }
    __syncthreads();
    #pragma unroll
    for (int p = 0; p < 4; ++p) {
        ushort4 v;
        v.x = tile[tc + 0][tr + 16 * p];
        v.y = tile[tc + 1][tr + 16 * p];
        v.z = tile[tc + 2][tr + 16 * p];
        v.w = tile[tc + 3][tr + 16 * p];
        *(ushort4*)(ob + (long)(c0 + tr + 16 * p) * 960 + r0 + tc) = v;
    }
}

// ---------------------------------------------------------------------------
// bf16 MFMA GEMM NT + fused instnorm stats. BK=32, 2-phase dbuf, counted
// vmcnt(2). 512 threads / 8 waves, LDS 32 KB -> 4 blocks/CU (100% occ cap).
// Grid (NB, N/128, M/128): x = batch -> XCD, y = N-tile inner, z = M-tile.
// ---------------------------------------------------------------------------
__global__ __launch_bounds__(512)
void mfma_gemm_nt_stats(const ushort_t* __restrict__ A, const ushort_t* __restrict__ B,
                        float* __restrict__ C, float2* __restrict__ part,
                        int M, int N, int K, long sA, long sB, long sC, float alpha)
{
    __shared__ __align__(16) ushort_t lA[2][128 * 32];
    __shared__ __align__(16) ushort_t lB[2][128 * 32];
    const int bb = blockIdx.x;
    const int by = blockIdx.z, bx = blockIdx.y;   // by = M-tile, bx = N-tile
    const ushort_t* Ab = A + (long)bb * sA;
    const ushort_t* Bb = B + (long)bb * sB;
    const int row0 = by * 128, col0 = bx * 128;
    const int t = threadIdx.x, lane = t & 63, w = t >> 6;
    const int wr = w >> 1, wc = w & 1;
    const int srow = lane >> 2;                      // 0..15: row within wave group
    const int schunk = ((lane & 3) ^ (srow & 3)) * 8; // swizzled source k-offset
    int arow_s, brow_s;
    {
        int r = row0 + w * 16 + srow;  arow_s = r < M ? r : M - 1;
        int rb = col0 + w * 16 + srow; brow_s = rb < N ? rb : N - 1;
    }

    f32x4 acc[2][4];
    #pragma unroll
    for (int m = 0; m < 2; ++m)
        #pragma unroll
        for (int n = 0; n < 4; ++n)
            acc[m][n] = (f32x4){0.f, 0.f, 0.f, 0.f};

    auto stage = [&](int buf, int k0) {
        glds16(Ab + (long)arow_s * K + k0 + schunk, lA[buf] + (w * 16) * 32);
        glds16(Bb + (long)brow_s * K + k0 + schunk, lB[buf] + (w * 16) * 32);
    };
    auto compute = [&](int buf) {
        __builtin_amdgcn_s_setprio(1);
        const int kc = lane >> 4;                    // 0..3
        bf16x8 aF[2], bF[4];
        #pragma unroll
        for (int m = 0; m < 2; ++m) {
            int rl = wr * 32 + m * 16 + (lane & 15);
            aF[m] = *(const bf16x8*)(lA[buf] + rl * 32 + ((kc ^ (rl & 3)) * 8));
        }
        #pragma unroll
        for (int n = 0; n < 4; ++n) {
            int rl = wc * 64 + n * 16 + (lane & 15);
            bF[n] = *(const bf16x8*)(lB[buf] + rl * 32 + ((kc ^ (rl & 3)) * 8));
        }
        #pragma unroll
        for (int m = 0; m < 2; ++m)
            #pragma unroll
            for (int n = 0; n < 4; ++n)
                acc[m][n] = __builtin_amdgcn_mfma_f32_16x16x32_bf16(aF[m], bF[n], acc[m][n], 0, 0, 0);
        __builtin_amdgcn_s_setprio(0);
    };

    stage(0, 0);
    int cur = 0;
    for (int k0 = 32; k0 < K; k0 += 32) {
        stage(cur ^ 1, k0);
        asm volatile("s_waitcnt vmcnt(2)" ::: "memory");
        __builtin_amdgcn_sched_barrier(0);
        __builtin_amdgcn_s_barrier();
        compute(cur);
        __builtin_amdgcn_s_barrier();
        cur ^= 1;
    }
    asm volatile("s_waitcnt vmcnt(0)" ::: "memory");
    __builtin_amdgcn_sched_barrier(0);
    __builtin_amdgcn_s_barrier();
    compute(cur);

    const int cr0 = row0 + wr * 32 + (lane >> 4) * 4;
    const int cc0 = col0 + wc * 64 + (lane & 15);
    float* Cb = C + (long)bb * sC;
    float s1 = 0.f, s2 = 0.f;
    #pragma unroll
    for (int m = 0; m < 2; ++m) {
        #pragma unroll
        for (int n = 0; n < 4; ++n) {
            int ccol = cc0 + n * 16;
            if (ccol >= N) continue;
            #pragma unroll
            for (int r = 0; r < 4; ++r) {
                int crow = cr0 + m * 16 + r;
                if (crow < M) {
                    float v = acc[m][n][r] * alpha;
                    Cb[(long)crow * N + ccol] = v;
                    s1 += v; s2 += v * v;
                }
            }
        }
    }
    #pragma unroll
    for (int off = 32; off > 0; off >>= 1) {
        s1 += __shfl_down(s1, off);
        s2 += __shfl_down(s2, off);
    }
    __syncthreads();               // all ds_reads of lA done before aliasing
    float* rbuf = (float*)lA;
    if (lane == 0) { rbuf[w] = s1; rbuf[8 + w] = s2; }
    __syncthreads();
    if (t == 0) {
        float a1 = 0.f, a2 = 0.f;
        #pragma unroll
        for (int q = 0; q < 8; ++q) { a1 += rbuf[q]; a2 += rbuf[8 + q]; }
        part[((long)bb * 8 + by) * 8 + bx] = make_float2(a1, a2);
    }
}

// ---------------------------------------------------------------------------
// Table-driven bf16 MFMA GEMM NT, BK=32, N fixed 1024, 512 thr / 8 waves,
// 2-phase dbuf, counted vmcnt(2), LDS 32 KB. Grid (NB, 8, mt).
// ---------------------------------------------------------------------------
struct NTTab {
    const ushort_t* A[5];
    const ushort_t* B[5];
    void* C[5];
    long sA[5], sB[5], sC[5], ldb[5];
    int M[5], K[5], obf[5], mt0[5];
    int nseg;
};

__global__ __launch_bounds__(512)
void mfma_gemm_nt_tab(NTTab tab)
{
    __shared__ __align__(16) ushort_t lA[2][128 * 32];
    __shared__ __align__(16) ushort_t lB[2][128 * 32];
    const int bb = blockIdx.x;
    int si = 0;
    #pragma unroll
    for (int s = 1; s < 5; ++s)
        if (s < tab.nseg && (int)blockIdx.z >= tab.mt0[s]) si = s;
    const int M = tab.M[si], K = tab.K[si];
    const long ldb = tab.ldb[si];
    const ushort_t* Ab = tab.A[si] + (long)bb * tab.sA[si];
    const ushort_t* Bb = tab.B[si] + (long)bb * tab.sB[si];
    const int row0 = (blockIdx.z - tab.mt0[si]) * 128, col0 = blockIdx.y * 128;
    const int t = threadIdx.x, lane = t & 63, w = t >> 6;
    const int wr = w >> 1, wc = w & 1;
    const int srow = lane >> 2;
    const int schunk = ((lane & 3) ^ (srow & 3)) * 8;
    int arow_s, brow_s;
    {
        int r = row0 + w * 16 + srow;
        arow_s = r < M ? r : M - 1;
        brow_s = col0 + w * 16 + srow;   // N=1024, always valid
    }

    f32x4 acc[2][4];
    #pragma unroll
    for (int m = 0; m < 2; ++m)
        #pragma unroll
        for (int n = 0; n < 4; ++n)
            acc[m][n] = (f32x4){0.f, 0.f, 0.f, 0.f};

    auto stage = [&](int buf, int k0) {
        glds16(Ab + (long)arow_s * K + k0 + schunk, lA[buf] + (w * 16) * 32);
        glds16(Bb + (long)brow_s * ldb + k0 + schunk, lB[buf] + (w * 16) * 32);
    };
    auto compute = [&](int buf) {
        __builtin_amdgcn_s_setprio(1);
        const int kc = lane >> 4;
        bf16x8 aF[2], bF[4];
        #pragma unroll
        for (int m = 0; m < 2; ++m) {
            int rl = wr * 32 + m * 16 + (lane & 15);
            aF[m] = *(const bf16x8*)(lA[buf] + rl * 32 + ((kc ^ (rl & 3)) * 8));
        }
        #pragma unroll
        for (int n = 0; n < 4; ++n) {
            int rl = wc * 64 + n * 16 + (lane & 15);
            bF[n] = *(const bf16x8*)(lB[buf] + rl * 32 + ((kc ^ (rl & 3)) * 8));
        }
        #pragma unroll
        for (int m = 0; m < 2; ++m)
            #pragma unroll
            for (int n = 0; n < 4; ++n)
                acc[m][n] = __builtin_amdgcn_mfma_f32_16x16x32_bf16(aF[m], bF[n], acc[m][n], 0, 0, 0);
        __builtin_amdgcn_s_setprio(0);
    };

    stage(0, 0);
    int cur = 0;
    for (int k0 = 32; k0 < K; k0 += 32) {
        stage(cur ^ 1, k0);
        asm volatile("s_waitcnt vmcnt(2)" ::: "memory");
        __builtin_amdgcn_sched_barrier(0);
        __builtin_amdgcn_s_barrier();
        compute(cur);
        __builtin_amdgcn_s_barrier();
        cur ^= 1;
    }
    asm volatile("s_waitcnt vmcnt(0)" ::: "memory");
    __builtin_amdgcn_sched_barrier(0);
    __builtin_amdgcn_s_barrier();
    compute(cur);

    const int cr0 = row0 + wr * 32 + (lane >> 4) * 4;
    const int cc0 = col0 + wc * 64 + (lane & 15);
    const int obf = tab.obf[si];
    ushort_t* Cb_b = (ushort_t*)tab.C[si] + (long)bb * tab.sC[si];
    float* Cb_f = (float*)tab.C[si] + (long)bb * tab.sC[si];
    #pragma unroll
    for (int m = 0; m < 2; ++m) {
        #pragma unroll
        for (int n = 0; n < 4; ++n) {
            int ccol = cc0 + n * 16;
            #pragma unroll
            for (int r = 0; r < 4; ++r) {
                int crow = cr0 + m * 16 + r;
                if (crow < M) {
                    float v = acc[m][n][r];
                    if (obf) Cb_b[(long)crow * 1024 + ccol] = f2bf(v);
                    else     Cb_f[(long)crow * 1024 + ccol] = v;
                }
            }
        }
    }
}

// ---------------------------------------------------------------------------
// Fused stencil launch: depthwise 3x3 on Q/K/V (l2norm on Q,K) + grouped
// 3x3 conv + l2norm for all branches.
// ---------------------------------------------------------------------------
__global__ __launch_bounds__(256)
void stencil_all(const ushort_t* __restrict__ Xqkv, const ushort_t* __restrict__ mh_x,
                 const float* __restrict__ w_qc, const float* __restrict__ w_kc,
                 const float* __restrict__ w_vc,
                 const float* __restrict__ wq1, const float* __restrict__ wq2,
                 const float* __restrict__ wq3, const float* __restrict__ wq4,
                 ushort_t* __restrict__ Qc, ushort_t* __restrict__ Kc,
                 ushort_t* __restrict__ Vc, ushort_t* __restrict__ q_all)
{
    __shared__ float p0[32 * 33];
    __shared__ float p1[32 * 33];
    __shared__ float red[5];
    const int bid = blockIdx.x;
    const int t = threadIdx.x;
    const int i0 = t * 4, y = i0 >> 5, x0 = i0 & 31;

    if (bid < 23040) {
        const int which = bid / 7680;
        const int p = bid - which * 7680;
        const int b = p / 960, c = p - b * 960;
        const ushort_t* ip = Xqkv + ((long)b * 2880 + which * 960 + c) * 1024;
        const float* wgt = (which == 0 ? w_qc : which == 1 ? w_kc : w_vc) + c * 9;
        ushort_t* op = (which == 0 ? Qc : which == 1 ? Kc : Vc) + (long)p * 1024;
        ushort4 u = *(const ushort4*)(ip + i0);
        float* rw = p0 + y * 33 + x0;
        rw[0] = bf2f(u.x); rw[1] = bf2f(u.y); rw[2] = bf2f(u.z); rw[3] = bf2f(u.w);
        __syncthreads();
        float W[9];
        #pragma unroll
        for (int q = 0; q < 9; ++q) W[q] = wgt[q];
        float r[3][6];
        #pragma unroll
        for (int dy = 0; dy < 3; ++dy) {
            int yy = y + dy - 1;
            bool vy = (unsigned)yy < 32u;
            #pragma unroll
            for (int j = 0; j < 6; ++j) {
                int xx = x0 - 1 + j;
                r[dy][j] = (vy && (unsigned)xx < 32u) ? p0[yy * 33 + xx] : 0.f;
            }
        }
        float o[4];
        #pragma unroll
        for (int q = 0; q < 4; ++q)
            o[q] = r[0][q] * W[0] + r[0][q + 1] * W[1] + r[0][q + 2] * W[2]
                 + r[1][q] * W[3] + r[1][q + 1] * W[4] + r[1][q + 2] * W[5]
                 + r[2][q] * W[6] + r[2][q + 1] * W[7] + r[2][q + 2] * W[8];
        float inv = 1.f;
        if (which < 2) {
            float s = o[0] * o[0] + o[1] * o[1] + o[2] * o[2] + o[3] * o[3];
            #pragma unroll
            for (int off = 32; off > 0; off >>= 1) s += __shfl_down(s, off);
            if ((t & 63) == 0) red[t >> 6] = s;
            __syncthreads();
            if (t == 0) red[4] = 1.0f / fmaxf(sqrtf(red[0] + red[1] + red[2] + red[3]), 1e-12f);
            __syncthreads();
            inv = red[4];
        }
        *(ushort4*)(op + i0) =
            make_ushort4(f2bf(o[0] * inv), f2bf(o[1] * inv), f2bf(o[2] * inv), f2bf(o[3] * inv));
        return;
    }
    const int po = bid - 23040;
    const int o = po & 1023, b = po >> 10;
    ushort_t* op = q_all + (long)po * 1024;
    int off; const float* wbase;
    if (o < 64)       { off = 0;   wbase = wq1; }
    else if (o < 128) { *(ushort4*)(op + i0) = make_ushort4(0, 0, 0, 0); return; }
    else if (o < 256) { off = 128; wbase = wq2; }
    else if (o < 512) { off = 256; wbase = wq3; }
    else              { off = 512; wbase = wq4; }
    const int ol = o - off;
    const int g2 = ol & ~1;
    const ushort_t* ip0 = mh_x + ((long)(b << 10) + off + g2) * 1024;
    const ushort_t* ip1 = ip0 + 1024;
    ushort4 u0 = *(const ushort4*)(ip0 + i0);
    ushort4 u1 = *(const ushort4*)(ip1 + i0);
    float* r0w = p0 + y * 33 + x0;
    float* r1w = p1 + y * 33 + x0;
    r0w[0] = bf2f(u0.x); r0w[1] = bf2f(u0.y); r0w[2] = bf2f(u0.z); r0w[3] = bf2f(u0.w);
    r1w[0] = bf2f(u1.x); r1w[1] = bf2f(u1.y); r1w[2] = bf2f(u1.z); r1w[3] = bf2f(u1.w);
    __syncthreads();
    const float* wp = wbase + ol * 18;
    float W[18];
    #pragma unroll
    for (int q = 0; q < 18; ++q) W[q] = wp[q];
    float o4[4] = {0.f, 0.f, 0.f, 0.f};
    #pragma unroll
    for (int pl = 0; pl < 2; ++pl) {
        const float* src = pl ? p1 : p0;
        const float* Wp = W + pl * 9;
        float r[3][6];
        #pragma unroll
        for (int dy = 0; dy < 3; ++dy) {
            int yy = y + dy - 1;
            bool vy = (unsigned)yy < 32u;
            #pragma unroll
            for (int j = 0; j < 6; ++j) {
                int xx = x0 - 1 + j;
                r[dy][j] = (vy && (unsigned)xx < 32u) ? src[yy * 33 + xx] : 0.f;
            }
        }
        #pragma unroll
        for (int q = 0; q < 4; ++q)
            o4[q] += r[0][q] * Wp[0] + r[0][q + 1] * Wp[1] + r[0][q + 2] * Wp[2]
                   + r[1][q] * Wp[3] + r[1][q + 1] * Wp[4] + r[1][q + 2] * Wp[5]
                   + r[2][q] * Wp[6] + r[2][q + 1] * Wp[7] + r[2][q + 2] * Wp[8];
    }
    float s = o4[0] * o4[0] + o4[1] * o4[1] + o4[2] * o4[2] + o4[3] * o4[3];
    #pragma unroll
    for (int off2 = 32; off2 > 0; off2 >>= 1) s += __shfl_down(s, off2);
    if ((t & 63) == 0) red[t >> 6] = s;
    __syncthreads();
    if (t == 0) red[4] = 1.0f / fmaxf(sqrtf(red[0] + red[1] + red[2] + red[3]), 1e-12f);
    __syncthreads();
    float inv = red[4];
    *(ushort4*)(op + i0) =
        make_ushort4(f2bf(o4[0] * inv), f2bf(o4[1] * inv), f2bf(o4[2] * inv), f2bf(o4[3] * inv));
}

// ---------------------------------------------------------------------------
// Instance-norm + softmax (row length 960), f32 in -> bf16 out (sim path).
// Stats computed in-block from `part` (64 float2 per batch).
// ---------------------------------------------------------------------------
__global__ __launch_bounds__(256)
void instnorm_softmax_bf16(const float* __restrict__ x, ushort_t* __restrict__ out,
                           const float2* __restrict__ part, int rowsPerB, float invL)
{
    int row = blockIdx.x;
    int b = row / rowsPerB;
    __shared__ float sMean, sRinv;
    int t = threadIdx.x;
    if (t < 64) {
        float2 p = part[b * 64 + t];
        float s1 = p.x, s2 = p.y;
        #pragma unroll
        for (int off = 32; off > 0; off >>= 1) {
            s1 += __shfl_down(s1, off);
            s2 += __shfl_down(s2, off);
        }
        if (t == 0) {
            float mean = s1 * invL;
            float var = s2 * invL - mean * mean;
            sMean = mean;
            sRinv = rsqrtf(var + 1e-5f);
        }
    }
    __syncthreads();
    float mean = sMean, rinv = sRinv;
    const float* xr = x + (long)row * 960;
    ushort_t* orow = out + (long)row * 960;
    float v[4];
    float mx = -1e30f;
    #pragma unroll
    for (int q = 0; q < 4; ++q) {
        int i = t + q * 256;
        if (i < 960) { v[q] = (xr[i] - mean) * rinv; mx = fmaxf(mx, v[q]); }
        else v[q] = -1e30f;
    }
    #pragma unroll
    for (int off = 32; off > 0; off >>= 1) mx = fmaxf(mx, __shfl_down(mx, off));
    __shared__ float rm[4];
    __shared__ float bmax, bsuminv;
    if ((t & 63) == 0) rm[t >> 6] = mx;
    __syncthreads();
    if (t == 0) bmax = fmaxf(fmaxf(rm[0], rm[1]), fmaxf(rm[2], rm[3]));
    __syncthreads();
    float mall = bmax;
    float s = 0.f;
    #pragma unroll
    for (int q = 0; q < 4; ++q) {
        int i = t + q * 256;
        if (i < 960) { v[q] = __expf(v[q] - mall); s += v[q]; }
    }
    #pragma unroll
    for (int off = 32; off > 0; off >>= 1) s += __shfl_down(s, off);
    if ((t & 63) == 0) rm[t >> 6] = s;
    __syncthreads();
    if (t == 0) bsuminv = 1.0f / (rm[0] + rm[1] + rm[2] + rm[3]);
    __syncthreads();
    float invS = bsuminv;
    #pragma unroll
    for (int q = 0; q < 4; ++q) {
        int i = t + q * 256;
        if (i < 960) orow[i] = f2bf(v[q] * invS);
    }
}

// ---------------------------------------------------------------------------
// Batched branch instnorm+softmax: rows [b][1024][960]; pad rows -> zeros.
// Branch stats computed in-block from `part` (8x8 per batch).
// ---------------------------------------------------------------------------
__global__ __launch_bounds__(256)
void softmax_attn_kernel(const float* __restrict__ x, ushort_t* __restrict__ P,
                         const float2* __restrict__ part)
{
    const int r = blockIdx.x & 1023, b = blockIdx.x >> 10;
    const int t = threadIdx.x;
    ushort_t* orow = P + ((long)(b << 10) + r) * 960;
    int br; float cnt;
    if (r < 64)       { br = 0; cnt = 64.f; }
    else if (r < 128) {
        #pragma unroll
        for (int q = 0; q < 4; ++q) {
            int i = t + q * 256;
            if (i < 960) orow[i] = 0;
        }
        return;
    }
    else if (r < 256) { br = 1; cnt = 128.f; }
    else if (r < 512) { br = 2; cnt = 256.f; }
    else              { br = 3; cnt = 512.f; }
    float invL = 1.0f / (cnt * 960.f);
    __shared__ float sMean, sRinv;
    if (t < 8) {
        const int lo4[4] = {0, 1, 2, 4}, hi4[4] = {1, 2, 4, 8};
        float s1 = 0.f, s2 = 0.f;
        for (int my = lo4[br]; my < hi4[br]; ++my) {
            float2 p = part[(b * 8 + my) * 8 + t];
            s1 += p.x; s2 += p.y;
        }
        #pragma unroll
        for (int off = 4; off > 0; off >>= 1) {
            s1 += __shfl_down(s1, off);
            s2 += __shfl_down(s2, off);
        }
        if (t == 0) {
            float mean = s1 * invL;
            float var = s2 * invL - mean * mean;
            sMean = mean;
            sRinv = rsqrtf(var + 1e-5f);
        }
    }
    __syncthreads();
    float mean = sMean, rinv = sRinv;
    const float* xr = x + ((long)(b << 10) + r) * 960;
    float v[4];
    float mx = -1e30f;
    #pragma unroll
    for (int q = 0; q < 4; ++q) {
        int i = t + q * 256;
        if (i < 960) { v[q] = (xr[i] - mean) * rinv; mx = fmaxf(mx, v[q]); }
        else v[q] = -1e30f;
    }
    #pragma unroll
    for (int off = 32; off > 0; off >>= 1) mx = fmaxf(mx, __shfl_down(mx, off));
    __shared__ float rm[4];
    __shared__ float bmax, bsuminv;
    if ((t & 63) == 0) rm[t >> 6] = mx;
    __syncthreads();
    if (t == 0) bmax = fmaxf(fmaxf(rm[0], rm[1]), fmaxf(rm[2], rm[3]));
    __syncthreads();
    float mall = bmax;
    float s = 0.f;
    #pragma unroll
    for (int q = 0; q < 4; ++q) {
        int i = t + q * 256;
        if (i < 960) { v[q] = __expf(v[q] - mall); s += v[q]; }
    }
    #pragma unroll
    for (int off = 32; off > 0; off >>= 1) s += __shfl_down(s, off);
    if ((t & 63) == 0) rm[t >> 6] = s;
    __syncthreads();
    if (t == 0) bsuminv = 1.0f / (rm[0] + rm[1] + rm[2] + rm[3]);
    __syncthreads();
    float invS = bsuminv;
    #pragma unroll
    for (int q = 0; q < 4; ++q) {
        int i = t + q * 256;
        if (i < 960) orow[i] = f2bf(v[q] * invS);
    }
}

// ---------------------------------------------------------------------------

extern "C" void kernel_launch(void* const* d_in, const int* in_sizes, int n_in,
                              void* d_out, int out_size, void* d_ws, size_t ws_size,
                              hipStream_t stream)
{
    const float* emb[4]  = {(const float*)d_in[0], (const float*)d_in[1],
                            (const float*)d_in[2], (const float*)d_in[3]};
    const float* emb_all = (const float*)d_in[4];
    const float* w_mh[4] = {(const float*)d_in[5], (const float*)d_in[6],
                            (const float*)d_in[7], (const float*)d_in[8]};
    const float* w_mq = (const float*)d_in[9];
    const float* w_mk = (const float*)d_in[10];
    const float* w_mv = (const float*)d_in[11];
    const float* w_q[4] = {(const float*)d_in[12], (const float*)d_in[13],
                           (const float*)d_in[14], (const float*)d_in[15]};
    const float* w_qc = (const float*)d_in[16];
    const float* w_kc = (const float*)d_in[17];
    const float* w_vc = (const float*)d_in[18];
    const float* w_proj[4] = {(const float*)d_in[19], (const float*)d_in[20],
                              (const float*)d_in[21], (const float*)d_in[22]};
    float* out = (float*)d_out;

    // ---- arena (element offsets into ushort_t* U) ----
    ushort_t* U = (ushort_t*)d_ws;
    const long eWQKV = 0;          // 2,764,800  (WQ|WK|WV, k-contig rows)
    const long eWMH  = 2764800;    // 348,160
    const long eWPJ  = 3112960;    // 348,160
    const long eR1   = 3461120;    // embT_all -> Vc -> ctx       (7,864,320)
    const long eR2   = 11325440;   // embT_i  -> VcT -> ctxT      (7,864,320)
    const long eR3   = 19189760;   // Xqkv (23,592,960) -> S6 f32(15,728,640 us) + Pc -> oT
    const long ePc   = 34918400;   // Pc (7,372,800) ends 42,291,200
    const long eR4   = 42782720;   // mh_x -> P_all               (8,388,608)
    const long eQc   = 51171328;   // Qc (7,864,320)
    const long eKc   = 59035648;   // Kc (7,864,320)
    const long eQall = 66899968;   // q_all (8,388,608) ends 75,288,576
    float2* part  = (float2*)(U + 75288576);

    ushort_t* WQKVb = U + eWQKV;
    ushort_t* WMHb  = U + eWMH;
    ushort_t* WPJb  = U + eWPJ;
    ushort_t* embT_all = U + eR1;
    ushort_t* Vc    = U + eR1;
    ushort_t* ctx   = U + eR1;
    ushort_t* VcT   = U + eR2;
    ushort_t* ctxT  = U + eR2;
    ushort_t* Xqkv  = U + eR3;
    float*    S6    = (float*)(U + eR3);
    ushort_t* oT    = U + eR3;
    ushort_t* Pc    = U + ePc;
    ushort_t* mh_x  = U + eR4;
    ushort_t* P_all = U + eR4;
    ushort_t* QcB   = U + eQc;
    ushort_t* KcB   = U + eKc;
    ushort_t* q_all = U + eQall;
    ushort_t* embT_i[4] = {U + eR2, U + eR2 + 524288, U + eR2 + 1572864, U + eR2 + 3670016};

    const float scale = 0.0322748612183951400f;   // 1/sqrt(960)
    const long SB = (long)KVC * HWN;              // 983040
    const long S1024 = 1024L * 1024;
    const int CH[4] = {64, 128, 256, 512};
    const int mhoff[4] = {0, 4096, 20480, 86016};
    const int rowOff[4] = {0, 128, 256, 512};
    const long outOff[4] = {0, 524288, 1572864, 3670016};
    dim3 blk(256);
    dim3 blk512(512);

    // ---- f2b weights (plain) ----
    {
        F2BTab tf;
        const float* fs[11] = {w_mq, w_mk, w_mv, w_mh[0], w_mh[1], w_mh[2], w_mh[3],
                               w_proj[0], w_proj[1], w_proj[2], w_proj[3]};
        long fd[11] = {eWQKV, eWQKV + 921600, eWQKV + 1843200,
                       eWMH + 0, eWMH + 4096, eWMH + 20480, eWMH + 86016,
                       eWPJ + 0, eWPJ + 4096, eWPJ + 20480, eWPJ + 86016};
        int fn[11] = {900, 900, 900, 4, 16, 64, 256, 4, 16, 64, 256};
        int ftot = 0;
        for (int i = 0; i < 11; ++i) { tf.src[i] = fs[i]; tf.dstOff[i] = fd[i]; tf.nblk[i] = fn[i]; ftot += fn[i]; }
        tf.nseg = 11;
        f2b_batched<<<ftot, blk, 0, stream>>>(tf, U);
    }
    // ---- f2bT embeddings (transpose-convert) ----
    {
        F2TTab tt;
        const float* ts[5] = {emb_all, emb[0], emb[1], emb[2], emb[3]};
        long td[5] = {eR1, eR2, eR2 + 524288, eR2 + 1572864, eR2 + 3670016};
        int tR[5] = {960, 64, 128, 256, 512};
        int tn[5];
        long tsi[5], tso[5];
        int ttot = 0;
        for (int i = 0; i < 5; ++i) {
            tsi[i] = (long)tR[i] * 1024; tso[i] = tsi[i];
            tn[i] = NB * (tR[i] / 64) * 16; ttot += tn[i];
            tt.src[i] = ts[i]; tt.dstOff[i] = td[i]; tt.R[i] = tR[i];
            tt.sIn[i] = tsi[i]; tt.sOut[i] = tso[i]; tt.nblk[i] = tn[i];
        }
        tt.nseg = 5;
        f2bt_batched<<<ttot, blk, 0, stream>>>(tt, U);
    }

    auto nt1 = [&](const ushort_t* A, long sA, const ushort_t* B, long sB, long ldb,
                   void* C, long sC, int M, int K, int obf) {
        NTTab tb;
        for (int s = 0; s < 5; ++s) {
            tb.A[s] = A; tb.B[s] = B; tb.C[s] = C;
            tb.sA[s] = sA; tb.sB[s] = sB; tb.sC[s] = sC; tb.ldb[s] = ldb;
            tb.M[s] = M; tb.K[s] = K; tb.obf[s] = obf; tb.mt0[s] = (s == 0) ? 0 : (1 << 30);
        }
        tb.nseg = 1;
        dim3 g(NB, 8, (M + 127) / 128);
        mfma_gemm_nt_tab<<<g, blk512, 0, stream>>>(tb);
    };

    // ---- stage 1: QKV (M=2880) + 4x mhead conv1x1, one NT launch ----
    {
        NTTab tb;
        tb.A[0] = WQKVb; tb.B[0] = embT_all; tb.C[0] = Xqkv;
        tb.sA[0] = 0; tb.sB[0] = SB; tb.sC[0] = 2880L * 1024; tb.ldb[0] = 960;
        tb.M[0] = 2880; tb.K[0] = 960; tb.obf[0] = 1; tb.mt0[0] = 0;
        int mt = 23;
        for (int i = 0; i < 4; ++i) {
            tb.A[1 + i] = WMHb + mhoff[i]; tb.B[1 + i] = embT_i[i];
            tb.C[1 + i] = mh_x + (long)rowOff[i] * 1024;
            tb.sA[1 + i] = 0; tb.sB[1 + i] = (long)CH[i] * 1024; tb.sC[1 + i] = S1024;
            tb.ldb[1 + i] = CH[i];
            tb.M[1 + i] = CH[i]; tb.K[1 + i] = CH[i]; tb.obf[1 + i] = 1; tb.mt0[1 + i] = mt;
            mt += (CH[i] + 127) / 128;
        }
        tb.nseg = 5;
        dim3 g(NB, 8, mt);   // (8, 8, 31): x = batch -> XCD, y = N-tile inner
        mfma_gemm_nt_tab<<<g, blk512, 0, stream>>>(tb);
    }

    // ---- stencils: dw(Q,K,V) + gconv, one launch ----
    stencil_all<<<31232, blk, 0, stream>>>(Xqkv, mh_x, w_qc, w_kc, w_vc,
                                           w_q[0], w_q[1], w_q[2], w_q[3],
                                           QcB, KcB, Vc, q_all);

    // ---- Vc -> VcT ----
    trb_kernel<<<dim3(16, 15, NB), blk, 0, stream>>>(Vc, VcT);

    // ---- sim = Qc @ Kc^T * scale + stats ----
    mfma_gemm_nt_stats<<<dim3(NB, 8, 8), blk512, 0, stream>>>(
        QcB, KcB, S6, part, KVC, KVC, HWN, SB, SB, (long)KVC * KVC, scale);
    instnorm_softmax_bf16<<<NB * KVC, blk, 0, stream>>>(S6, Pc, part, KVC,
                                                        1.f / ((float)KVC * (float)KVC));

    // ---- ctx = NT(Pc, VcT) -> [960][1024] bf16 ----
    nt1(Pc, (long)KVC * KVC, VcT, SB, 960, ctx, SB, KVC, KVC, 1);

    // ---- ctx -> ctxT ----
    trb_kernel<<<dim3(16, 15, NB), blk, 0, stream>>>(ctx, ctxT);

    // ---- attn = q_all @ ctx^T * scale + stats ----
    mfma_gemm_nt_stats<<<dim3(NB, 8, 8), blk512, 0, stream>>>(
        q_all, ctx, S6, part, 1024, KVC, HWN, S1024, SB, SB, scale);
    softmax_attn_kernel<<<NB * 1024, blk, 0, stream>>>(S6, P_all, part);

    // ---- oT = NT(ctxT, P_all) -> [1024 hw][1024 ch] bf16 ----
    nt1(ctxT, SB, P_all, SB, 960, oT, S1024, 1024, KVC, 1);

    // ---- proj: 4 branches, one NT table launch (f32 out) ----
    {
        NTTab tb;
        int mt = 0;
        for (int i = 0; i < 4; ++i) {
            tb.A[i] = WPJb + mhoff[i]; tb.B[i] = oT + rowOff[i];
            tb.C[i] = out + outOff[i];
            tb.sA[i] = 0; tb.sB[i] = S1024; tb.sC[i] = (long)CH[i] * 1024;
            tb.ldb[i] = 1024;
            tb.M[i] = CH[i]; tb.K[i] = CH[i]; tb.obf[i] = 0; tb.mt0[i] = mt;
            mt += (CH[i] + 127) / 128;
        }
        tb.A[4] = tb.A[3]; tb.B[4] = tb.B[3]; tb.C[4] = tb.C[3];
        tb.sA[4] = 0; tb.sB[4] = 0; tb.sC[4] = 0; tb.ldb[4] = 1024;
        tb.M[4] = 1; tb.K[4] = 64; tb.obf[4] = 0; tb.mt0[4] = 1 << 30;
        tb.nseg = 4;
        dim3 g(NB, 8, mt);   // (8, 8, 8)
        mfma_gemm_nt_tab<<<g, blk512, 0, stream>>>(tb);
    }

    (void)in_sizes; (void)n_in; (void)out_size; (void)ws_size;
}

// Round 12
// 283.035 us; speedup vs baseline: 1.0676x; 1.0676x over previous
//
#include <hip/hip_runtime.h>
#include <hip/hip_bf16.h>
#include <math.h>

#define NB 8
#define HWN 1024
#define KVC 960

typedef short bf16x8 __attribute__((ext_vector_type(8)));
typedef float f32x4 __attribute__((ext_vector_type(4)));
typedef unsigned short ushort_t;

__device__ inline ushort_t f2bf(float f) {
    __hip_bfloat16 h = __float2bfloat16(f);
    return *reinterpret_cast<ushort_t*>(&h);
}
__device__ inline float bf2f(ushort_t u) {
    union { float f; unsigned int i; } x; x.i = ((unsigned int)u) << 16; return x.f;
}
__device__ inline void glds16(const ushort_t* src, ushort_t* dst) {
    __builtin_amdgcn_global_load_lds(
        (const __attribute__((address_space(1))) void*)src,
        (__attribute__((address_space(3))) void*)dst, 16, 0, 0);
}

// ---------------------------------------------------------------------------
// Batched f32 -> bf16 convert (no transpose). 1024 elems per block.
// ---------------------------------------------------------------------------
struct F2BTab {
    const float* src[12];
    long dstOff[12];
    int nblk[12];
    int nseg;
};

__global__ __launch_bounds__(256)
void f2b_batched(F2BTab tab, ushort_t* base)
{
    int b = blockIdx.x, s = 0;
    while (s < tab.nseg - 1 && b >= tab.nblk[s]) { b -= tab.nblk[s]; ++s; }
    float4 v = *((const float4*)tab.src[s] + (long)b * 256 + threadIdx.x);
    ushort4 o = make_ushort4(f2bf(v.x), f2bf(v.y), f2bf(v.z), f2bf(v.w));
    *((ushort4*)(base + tab.dstOff[s]) + (long)b * 256 + threadIdx.x) = o;
}

// ---------------------------------------------------------------------------
// Batched f32 -> bf16 transpose-convert: in [b][R][1024] f32 -> out [b][1024][R].
// ---------------------------------------------------------------------------
struct F2TTab {
    const float* src[5];
    long dstOff[5];
    long sIn[5], sOut[5];
    int R[5];
    int nblk[5];
    int nseg;
};

__global__ __launch_bounds__(256)
void f2bt_batched(F2TTab tab, ushort_t* base)
{
    __shared__ ushort_t tile[64][65];
    int b = blockIdx.x, s = 0;
    while (s < tab.nseg - 1 && b >= tab.nblk[s]) { b -= tab.nblk[s]; ++s; }
    const int R = tab.R[s];
    const int tpb = (R >> 6) * 16;
    const int batch = b / tpb, rem = b - batch * tpb;
    const int rtile = rem >> 4, ctile = rem & 15;
    const float* ib = tab.src[s] + (long)batch * tab.sIn[s] + (long)(rtile * 64) * 1024 + ctile * 64;
    const int t = threadIdx.x, tr = t >> 4, tc = (t & 15) * 4;
    #pragma unroll
    for (int p = 0; p < 4; ++p) {
        float4 v = *(const float4*)(ib + (long)(tr + 16 * p) * 1024 + tc);
        tile[tr + 16 * p][tc + 0] = f2bf(v.x);
        tile[tr + 16 * p][tc + 1] = f2bf(v.y);
        tile[tr + 16 * p][tc + 2] = f2bf(v.z);
        tile[tr + 16 * p][tc + 3] = f2bf(v.w);
    }
    __syncthreads();
    ushort_t* ob = base + tab.dstOff[s] + (long)batch * tab.sOut[s]
                 + (long)(ctile * 64) * R + rtile * 64;
    #pragma unroll
    for (int p = 0; p < 4; ++p) {
        ushort4 v;
        v.x = tile[tc + 0][tr + 16 * p];
        v.y = tile[tc + 1][tr + 16 * p];
        v.z = tile[tc + 2][tr + 16 * p];
        v.w = tile[tc + 3][tr + 16 * p];
        *(ushort4*)(ob + (long)(tr + 16 * p) * R + tc) = v;
    }
}

// ---------------------------------------------------------------------------
// bf16 transpose: in [b][960][1024] -> out [b][1024][960]. grid (16,15,NB).
// ---------------------------------------------------------------------------
__global__ __launch_bounds__(256)
void trb_kernel(const ushort_t* __restrict__ in, ushort_t* __restrict__ out)
{
    __shared__ ushort_t tile[64][65];
    const int r0 = blockIdx.y * 64, c0 = blockIdx.x * 64;
    const long sP = (long)KVC * HWN;
    const ushort_t* ib = in + (long)blockIdx.z * sP;
    ushort_t* ob = out + (long)blockIdx.z * sP;
    const int t = threadIdx.x, tr = t >> 4, tc = (t & 15) * 4;
    #pragma unroll
    for (int p = 0; p < 4; ++p) {
        ushort4 v = *(const ushort4*)(ib + (long)(r0 + tr + 16 * p) * 1024 + c0 + tc);
        tile[tr + 16 * p][tc + 0] = v.x;
        tile[tr + 16 * p][tc + 1] = v.y;
        tile[tr + 16 * p][tc + 2] = v.z;
        tile[tr + 16 * p][tc + 3] = v.w;
    }
    __syncthreads();
    #pragma unroll
    for (int p = 0; p < 4; ++p) {
        ushort4 v;
        v.x = tile[tc + 0][tr + 16 * p];
        v.y = tile[tc + 1][tr + 16 * p];
        v.z = tile[tc + 2][tr + 16 * p];
        v.w = tile[tc + 3][tr + 16 * p];
        *(ushort4*)(ob + (long)(c0 + tr + 16 * p) * 960 + r0 + tc) = v;
    }
}

// ---------------------------------------------------------------------------
// bf16 MFMA GEMM NT + fused instnorm stats. BK=64, 2-phase dbuf, counted
// vmcnt(4). 512 threads / 8 waves. Grid (NB, N/128, M/128):
// x = batch -> XCD, y = N-tile (inner, L2-reuses A-panel), z = M-tile.
// ---------------------------------------------------------------------------
__global__ __launch_bounds__(512)
void mfma_gemm_nt_stats(const ushort_t* __restrict__ A, const ushort_t* __restrict__ B,
                        float* __restrict__ C, float2* __restrict__ part,
                        int M, int N, int K, long sA, long sB, long sC, float alpha)
{
    __shared__ __align__(16) ushort_t lA[2][128 * 64];
    __shared__ __align__(16) ushort_t lB[2][128 * 64];
    const int bb = blockIdx.x;
    const int by = blockIdx.z, bx = blockIdx.y;   // by = M-tile, bx = N-tile
    const ushort_t* Ab = A + (long)bb * sA;
    const ushort_t* Bb = B + (long)bb * sB;
    const int row0 = by * 128, col0 = bx * 128;
    const int t = threadIdx.x, lane = t & 63, w = t >> 6;
    const int wr = w >> 1, wc = w & 1;
    const int arl = lane >> 3;
    const int acs = ((lane & 7) ^ arl) * 8;
    int arow[2], brow[2];
    #pragma unroll
    for (int j = 0; j < 2; ++j) {
        int r = row0 + w * 16 + j * 8 + arl;  arow[j] = r < M ? r : M - 1;
        int rb = col0 + w * 16 + j * 8 + arl; brow[j] = rb < N ? rb : N - 1;
    }

    f32x4 acc[2][4];
    #pragma unroll
    for (int m = 0; m < 2; ++m)
        #pragma unroll
        for (int n = 0; n < 4; ++n)
            acc[m][n] = (f32x4){0.f, 0.f, 0.f, 0.f};

    auto stage = [&](int buf, int k0) {
        #pragma unroll
        for (int j = 0; j < 2; ++j) {
            glds16(Ab + (long)arow[j] * K + k0 + acs, lA[buf] + (w * 16 + j * 8) * 64);
            glds16(Bb + (long)brow[j] * K + k0 + acs, lB[buf] + (w * 16 + j * 8) * 64);
        }
    };
    auto compute = [&](int buf) {
        __builtin_amdgcn_s_setprio(1);
        #pragma unroll
        for (int sub = 0; sub < 2; ++sub) {
            const int kc = (lane >> 4) + sub * 4;
            bf16x8 aF[2], bF[4];
            #pragma unroll
            for (int m = 0; m < 2; ++m) {
                int rl = wr * 32 + m * 16 + (lane & 15);
                aF[m] = *(const bf16x8*)(lA[buf] + rl * 64 + (kc ^ (rl & 7)) * 8);
            }
            #pragma unroll
            for (int n = 0; n < 4; ++n) {
                int rl = wc * 64 + n * 16 + (lane & 15);
                bF[n] = *(const bf16x8*)(lB[buf] + rl * 64 + (kc ^ (rl & 7)) * 8);
            }
            #pragma unroll
            for (int m = 0; m < 2; ++m)
                #pragma unroll
                for (int n = 0; n < 4; ++n)
                    acc[m][n] = __builtin_amdgcn_mfma_f32_16x16x32_bf16(aF[m], bF[n], acc[m][n], 0, 0, 0);
        }
        __builtin_amdgcn_s_setprio(0);
    };

    stage(0, 0);
    int cur = 0;
    for (int k0 = 64; k0 < K; k0 += 64) {
        stage(cur ^ 1, k0);
        asm volatile("s_waitcnt vmcnt(4)" ::: "memory");
        __builtin_amdgcn_sched_barrier(0);
        __builtin_amdgcn_s_barrier();
        compute(cur);
        __builtin_amdgcn_s_barrier();
        cur ^= 1;
    }
    asm volatile("s_waitcnt vmcnt(0)" ::: "memory");
    __builtin_amdgcn_sched_barrier(0);
    __builtin_amdgcn_s_barrier();
    compute(cur);

    const int cr0 = row0 + wr * 32 + (lane >> 4) * 4;
    const int cc0 = col0 + wc * 64 + (lane & 15);
    float* Cb = C + (long)bb * sC;
    float s1 = 0.f, s2 = 0.f;
    #pragma unroll
    for (int m = 0; m < 2; ++m) {
        #pragma unroll
        for (int n = 0; n < 4; ++n) {
            int ccol = cc0 + n * 16;
            if (ccol >= N) continue;
            #pragma unroll
            for (int r = 0; r < 4; ++r) {
                int crow = cr0 + m * 16 + r;
                if (crow < M) {
                    float v = acc[m][n][r] * alpha;
                    Cb[(long)crow * N + ccol] = v;
                    s1 += v; s2 += v * v;
                }
            }
        }
    }
    #pragma unroll
    for (int off = 32; off > 0; off >>= 1) {
        s1 += __shfl_down(s1, off);
        s2 += __shfl_down(s2, off);
    }
    __syncthreads();               // all ds_reads of lA done before aliasing
    float* rbuf = (float*)lA;
    if (lane == 0) { rbuf[w] = s1; rbuf[8 + w] = s2; }
    __syncthreads();
    if (t == 0) {
        float a1 = 0.f, a2 = 0.f;
        #pragma unroll
        for (int q = 0; q < 8; ++q) { a1 += rbuf[q]; a2 += rbuf[8 + q]; }
        part[((long)bb * 8 + by) * 8 + bx] = make_float2(a1, a2);
    }
}

// ---------------------------------------------------------------------------
// Table-driven bf16 MFMA GEMM NT, BK=64, N fixed 1024, 512 thr / 8 waves,
// 2-phase dbuf, counted vmcnt(4). Grid (NB, 8, mt).
// ---------------------------------------------------------------------------
struct NTTab {
    const ushort_t* A[5];
    const ushort_t* B[5];
    void* C[5];
    long sA[5], sB[5], sC[5], ldb[5];
    int M[5], K[5], obf[5], mt0[5];
    int nseg;
};

__global__ __launch_bounds__(512)
void mfma_gemm_nt_tab(NTTab tab)
{
    __shared__ __align__(16) ushort_t lA[2][128 * 64];
    __shared__ __align__(16) ushort_t lB[2][128 * 64];
    const int bb = blockIdx.x;
    int si = 0;
    #pragma unroll
    for (int s = 1; s < 5; ++s)
        if (s < tab.nseg && (int)blockIdx.z >= tab.mt0[s]) si = s;
    const int M = tab.M[si], K = tab.K[si];
    const long ldb = tab.ldb[si];
    const ushort_t* Ab = tab.A[si] + (long)bb * tab.sA[si];
    const ushort_t* Bb = tab.B[si] + (long)bb * tab.sB[si];
    const int row0 = (blockIdx.z - tab.mt0[si]) * 128, col0 = blockIdx.y * 128;
    const int t = threadIdx.x, lane = t & 63, w = t >> 6;
    const int wr = w >> 1, wc = w & 1;
    const int arl = lane >> 3;
    const int acs = ((lane & 7) ^ arl) * 8;
    int arow[2], brow[2];
    #pragma unroll
    for (int j = 0; j < 2; ++j) {
        int r = row0 + w * 16 + j * 8 + arl;
        arow[j] = r < M ? r : M - 1;
        brow[j] = col0 + w * 16 + j * 8 + arl;   // N=1024, always valid
    }

    f32x4 acc[2][4];
    #pragma unroll
    for (int m = 0; m < 2; ++m)
        #pragma unroll
        for (int n = 0; n < 4; ++n)
            acc[m][n] = (f32x4){0.f, 0.f, 0.f, 0.f};

    auto stage = [&](int buf, int k0) {
        #pragma unroll
        for (int j = 0; j < 2; ++j) {
            glds16(Ab + (long)arow[j] * K + k0 + acs, lA[buf] + (w * 16 + j * 8) * 64);
            glds16(Bb + (long)brow[j] * ldb + k0 + acs, lB[buf] + (w * 16 + j * 8) * 64);
        }
    };
    auto compute = [&](int buf) {
        __builtin_amdgcn_s_setprio(1);
        #pragma unroll
        for (int sub = 0; sub < 2; ++sub) {
            const int kc = (lane >> 4) + sub * 4;
            bf16x8 aF[2], bF[4];
            #pragma unroll
            for (int m = 0; m < 2; ++m) {
                int rl = wr * 32 + m * 16 + (lane & 15);
                aF[m] = *(const bf16x8*)(lA[buf] + rl * 64 + (kc ^ (rl & 7)) * 8);
            }
            #pragma unroll
            for (int n = 0; n < 4; ++n) {
                int rl = wc * 64 + n * 16 + (lane & 15);
                bF[n] = *(const bf16x8*)(lB[buf] + rl * 64 + (kc ^ (rl & 7)) * 8);
            }
            #pragma unroll
            for (int m = 0; m < 2; ++m)
                #pragma unroll
                for (int n = 0; n < 4; ++n)
                    acc[m][n] = __builtin_amdgcn_mfma_f32_16x16x32_bf16(aF[m], bF[n], acc[m][n], 0, 0, 0);
        }
        __builtin_amdgcn_s_setprio(0);
    };

    stage(0, 0);
    int cur = 0;
    for (int k0 = 64; k0 < K; k0 += 64) {
        stage(cur ^ 1, k0);
        asm volatile("s_waitcnt vmcnt(4)" ::: "memory");
        __builtin_amdgcn_sched_barrier(0);
        __builtin_amdgcn_s_barrier();
        compute(cur);
        __builtin_amdgcn_s_barrier();
        cur ^= 1;
    }
    asm volatile("s_waitcnt vmcnt(0)" ::: "memory");
    __builtin_amdgcn_sched_barrier(0);
    __builtin_amdgcn_s_barrier();
    compute(cur);

    const int cr0 = row0 + wr * 32 + (lane >> 4) * 4;
    const int cc0 = col0 + wc * 64 + (lane & 15);
    const int obf = tab.obf[si];
    ushort_t* Cb_b = (ushort_t*)tab.C[si] + (long)bb * tab.sC[si];
    float* Cb_f = (float*)tab.C[si] + (long)bb * tab.sC[si];
    #pragma unroll
    for (int m = 0; m < 2; ++m) {
        #pragma unroll
        for (int n = 0; n < 4; ++n) {
            int ccol = cc0 + n * 16;
            #pragma unroll
            for (int r = 0; r < 4; ++r) {
                int crow = cr0 + m * 16 + r;
                if (crow < M) {
                    float v = acc[m][n][r];
                    if (obf) Cb_b[(long)crow * 1024 + ccol] = f2bf(v);
                    else     Cb_f[(long)crow * 1024 + ccol] = v;
                }
            }
        }
    }
}

// ---------------------------------------------------------------------------
// Fused stencil launch: depthwise 3x3 on Q/K/V (l2norm on Q,K) + grouped
// 3x3 conv + l2norm for all branches.
// ---------------------------------------------------------------------------
__global__ __launch_bounds__(256)
void stencil_all(const ushort_t* __restrict__ Xqkv, const ushort_t* __restrict__ mh_x,
                 const float* __restrict__ w_qc, const float* __restrict__ w_kc,
                 const float* __restrict__ w_vc,
                 const float* __restrict__ wq1, const float* __restrict__ wq2,
                 const float* __restrict__ wq3, const float* __restrict__ wq4,
                 ushort_t* __restrict__ Qc, ushort_t* __restrict__ Kc,
                 ushort_t* __restrict__ Vc, ushort_t* __restrict__ q_all)
{
    __shared__ float p0[32 * 33];
    __shared__ float p1[32 * 33];
    __shared__ float red[5];
    const int bid = blockIdx.x;
    const int t = threadIdx.x;
    const int i0 = t * 4, y = i0 >> 5, x0 = i0 & 31;

    if (bid < 23040) {
        const int which = bid / 7680;
        const int p = bid - which * 7680;
        const int b = p / 960, c = p - b * 960;
        const ushort_t* ip = Xqkv + ((long)b * 2880 + which * 960 + c) * 1024;
        const float* wgt = (which == 0 ? w_qc : which == 1 ? w_kc : w_vc) + c * 9;
        ushort_t* op = (which == 0 ? Qc : which == 1 ? Kc : Vc) + (long)p * 1024;
        ushort4 u = *(const ushort4*)(ip + i0);
        float* rw = p0 + y * 33 + x0;
        rw[0] = bf2f(u.x); rw[1] = bf2f(u.y); rw[2] = bf2f(u.z); rw[3] = bf2f(u.w);
        __syncthreads();
        float W[9];
        #pragma unroll
        for (int q = 0; q < 9; ++q) W[q] = wgt[q];
        float r[3][6];
        #pragma unroll
        for (int dy = 0; dy < 3; ++dy) {
            int yy = y + dy - 1;
            bool vy = (unsigned)yy < 32u;
            #pragma unroll
            for (int j = 0; j < 6; ++j) {
                int xx = x0 - 1 + j;
                r[dy][j] = (vy && (unsigned)xx < 32u) ? p0[yy * 33 + xx] : 0.f;
            }
        }
        float o[4];
        #pragma unroll
        for (int q = 0; q < 4; ++q)
            o[q] = r[0][q] * W[0] + r[0][q + 1] * W[1] + r[0][q + 2] * W[2]
                 + r[1][q] * W[3] + r[1][q + 1] * W[4] + r[1][q + 2] * W[5]
                 + r[2][q] * W[6] + r[2][q + 1] * W[7] + r[2][q + 2] * W[8];
        float inv = 1.f;
        if (which < 2) {
            float s = o[0] * o[0] + o[1] * o[1] + o[2] * o[2] + o[3] * o[3];
            #pragma unroll
            for (int off = 32; off > 0; off >>= 1) s += __shfl_down(s, off);
            if ((t & 63) == 0) red[t >> 6] = s;
            __syncthreads();
            if (t == 0) red[4] = 1.0f / fmaxf(sqrtf(red[0] + red[1] + red[2] + red[3]), 1e-12f);
            __syncthreads();
            inv = red[4];
        }
        *(ushort4*)(op + i0) =
            make_ushort4(f2bf(o[0] * inv), f2bf(o[1] * inv), f2bf(o[2] * inv), f2bf(o[3] * inv));
        return;
    }
    const int po = bid - 23040;
    const int o = po & 1023, b = po >> 10;
    ushort_t* op = q_all + (long)po * 1024;
    int off; const float* wbase;
    if (o < 64)       { off = 0;   wbase = wq1; }
    else if (o < 128) { *(ushort4*)(op + i0) = make_ushort4(0, 0, 0, 0); return; }
    else if (o < 256) { off = 128; wbase = wq2; }
    else if (o < 512) { off = 256; wbase = wq3; }
    else              { off = 512; wbase = wq4; }
    const int ol = o - off;
    const int g2 = ol & ~1;
    const ushort_t* ip0 = mh_x + ((long)(b << 10) + off + g2) * 1024;
    const ushort_t* ip1 = ip0 + 1024;
    ushort4 u0 = *(const ushort4*)(ip0 + i0);
    ushort4 u1 = *(const ushort4*)(ip1 + i0);
    float* r0w = p0 + y * 33 + x0;
    float* r1w = p1 + y * 33 + x0;
    r0w[0] = bf2f(u0.x); r0w[1] = bf2f(u0.y); r0w[2] = bf2f(u0.z); r0w[3] = bf2f(u0.w);
    r1w[0] = bf2f(u1.x); r1w[1] = bf2f(u1.y); r1w[2] = bf2f(u1.z); r1w[3] = bf2f(u1.w);
    __syncthreads();
    const float* wp = wbase + ol * 18;
    float W[18];
    #pragma unroll
    for (int q = 0; q < 18; ++q) W[q] = wp[q];
    float o4[4] = {0.f, 0.f, 0.f, 0.f};
    #pragma unroll
    for (int pl = 0; pl < 2; ++pl) {
        const float* src = pl ? p1 : p0;
        const float* Wp = W + pl * 9;
        float r[3][6];
        #pragma unroll
        for (int dy = 0; dy < 3; ++dy) {
            int yy = y + dy - 1;
            bool vy = (unsigned)yy < 32u;
            #pragma unroll
            for (int j = 0; j < 6; ++j) {
                int xx = x0 - 1 + j;
                r[dy][j] = (vy && (unsigned)xx < 32u) ? src[yy * 33 + xx] : 0.f;
            }
        }
        #pragma unroll
        for (int q = 0; q < 4; ++q)
            o4[q] += r[0][q] * Wp[0] + r[0][q + 1] * Wp[1] + r[0][q + 2] * Wp[2]
                   + r[1][q] * Wp[3] + r[1][q + 1] * Wp[4] + r[1][q + 2] * Wp[5]
                   + r[2][q] * Wp[6] + r[2][q + 1] * Wp[7] + r[2][q + 2] * Wp[8];
    }
    float s = o4[0] * o4[0] + o4[1] * o4[1] + o4[2] * o4[2] + o4[3] * o4[3];
    #pragma unroll
    for (int off2 = 32; off2 > 0; off2 >>= 1) s += __shfl_down(s, off2);
    if ((t & 63) == 0) red[t >> 6] = s;
    __syncthreads();
    if (t == 0) red[4] = 1.0f / fmaxf(sqrtf(red[0] + red[1] + red[2] + red[3]), 1e-12f);
    __syncthreads();
    float inv = red[4];
    *(ushort4*)(op + i0) =
        make_ushort4(f2bf(o4[0] * inv), f2bf(o4[1] * inv), f2bf(o4[2] * inv), f2bf(o4[3] * inv));
}

// ---------------------------------------------------------------------------
// Instance-norm + softmax (row length 960), f32 in -> bf16 out (sim path).
// Stats computed in-block from `part` (64 float2 per batch).
// ---------------------------------------------------------------------------
__global__ __launch_bounds__(256)
void instnorm_softmax_bf16(const float* __restrict__ x, ushort_t* __restrict__ out,
                           const float2* __restrict__ part, int rowsPerB, float invL)
{
    int row = blockIdx.x;
    int b = row / rowsPerB;
    __shared__ float sMean, sRinv;
    int t = threadIdx.x;
    if (t < 64) {
        float2 p = part[b * 64 + t];
        float s1 = p.x, s2 = p.y;
        #pragma unroll
        for (int off = 32; off > 0; off >>= 1) {
            s1 += __shfl_down(s1, off);
            s2 += __shfl_down(s2, off);
        }
        if (t == 0) {
            float mean = s1 * invL;
            float var = s2 * invL - mean * mean;
            sMean = mean;
            sRinv = rsqrtf(var + 1e-5f);
        }
    }
    __syncthreads();
    float mean = sMean, rinv = sRinv;
    const float* xr = x + (long)row * 960;
    ushort_t* orow = out + (long)row * 960;
    float v[4];
    float mx = -1e30f;
    #pragma unroll
    for (int q = 0; q < 4; ++q) {
        int i = t + q * 256;
        if (i < 960) { v[q] = (xr[i] - mean) * rinv; mx = fmaxf(mx, v[q]); }
        else v[q] = -1e30f;
    }
    #pragma unroll
    for (int off = 32; off > 0; off >>= 1) mx = fmaxf(mx, __shfl_down(mx, off));
    __shared__ float rm[4];
    __shared__ float bmax, bsuminv;
    if ((t & 63) == 0) rm[t >> 6] = mx;
    __syncthreads();
    if (t == 0) bmax = fmaxf(fmaxf(rm[0], rm[1]), fmaxf(rm[2], rm[3]));
    __syncthreads();
    float mall = bmax;
    float s = 0.f;
    #pragma unroll
    for (int q = 0; q < 4; ++q) {
        int i = t + q * 256;
        if (i < 960) { v[q] = __expf(v[q] - mall); s += v[q]; }
    }
    #pragma unroll
    for (int off = 32; off > 0; off >>= 1) s += __shfl_down(s, off);
    if ((t & 63) == 0) rm[t >> 6] = s;
    __syncthreads();
    if (t == 0) bsuminv = 1.0f / (rm[0] + rm[1] + rm[2] + rm[3]);
    __syncthreads();
    float invS = bsuminv;
    #pragma unroll
    for (int q = 0; q < 4; ++q) {
        int i = t + q * 256;
        if (i < 960) orow[i] = f2bf(v[q] * invS);
    }
}

// ---------------------------------------------------------------------------
// Batched branch instnorm+softmax: rows [b][1024][960]; pad rows -> zeros.
// Branch stats computed in-block from `part` (8x8 per batch).
// ---------------------------------------------------------------------------
__global__ __launch_bounds__(256)
void softmax_attn_kernel(const float* __restrict__ x, ushort_t* __restrict__ P,
                         const float2* __restrict__ part)
{
    const int r = blockIdx.x & 1023, b = blockIdx.x >> 10;
    const int t = threadIdx.x;
    ushort_t* orow = P + ((long)(b << 10) + r) * 960;
    int br; float cnt;
    if (r < 64)       { br = 0; cnt = 64.f; }
    else if (r < 128) {
        #pragma unroll
        for (int q = 0; q < 4; ++q) {
            int i = t + q * 256;
            if (i < 960) orow[i] = 0;
        }
        return;
    }
    else if (r < 256) { br = 1; cnt = 128.f; }
    else if (r < 512) { br = 2; cnt = 256.f; }
    else              { br = 3; cnt = 512.f; }
    float invL = 1.0f / (cnt * 960.f);
    __shared__ float sMean, sRinv;
    if (t < 8) {
        const int lo4[4] = {0, 1, 2, 4}, hi4[4] = {1, 2, 4, 8};
        float s1 = 0.f, s2 = 0.f;
        for (int my = lo4[br]; my < hi4[br]; ++my) {
            float2 p = part[(b * 8 + my) * 8 + t];
            s1 += p.x; s2 += p.y;
        }
        #pragma unroll
        for (int off = 4; off > 0; off >>= 1) {
            s1 += __shfl_down(s1, off);
            s2 += __shfl_down(s2, off);
        }
        if (t == 0) {
            float mean = s1 * invL;
            float var = s2 * invL - mean * mean;
            sMean = mean;
            sRinv = rsqrtf(var + 1e-5f);
        }
    }
    __syncthreads();
    float mean = sMean, rinv = sRinv;
    const float* xr = x + ((long)(b << 10) + r) * 960;
    float v[4];
    float mx = -1e30f;
    #pragma unroll
    for (int q = 0; q < 4; ++q) {
        int i = t + q * 256;
        if (i < 960) { v[q] = (xr[i] - mean) * rinv; mx = fmaxf(mx, v[q]); }
        else v[q] = -1e30f;
    }
    #pragma unroll
    for (int off = 32; off > 0; off >>= 1) mx = fmaxf(mx, __shfl_down(mx, off));
    __shared__ float rm[4];
    __shared__ float bmax, bsuminv;
    if ((t & 63) == 0) rm[t >> 6] = mx;
    __syncthreads();
    if (t == 0) bmax = fmaxf(fmaxf(rm[0], rm[1]), fmaxf(rm[2], rm[3]));
    __syncthreads();
    float mall = bmax;
    float s = 0.f;
    #pragma unroll
    for (int q = 0; q < 4; ++q) {
        int i = t + q * 256;
        if (i < 960) { v[q] = __expf(v[q] - mall); s += v[q]; }
    }
    #pragma unroll
    for (int off = 32; off > 0; off >>= 1) s += __shfl_down(s, off);
    if ((t & 63) == 0) rm[t >> 6] = s;
    __syncthreads();
    if (t == 0) bsuminv = 1.0f / (rm[0] + rm[1] + rm[2] + rm[3]);
    __syncthreads();
    float invS = bsuminv;
    #pragma unroll
    for (int q = 0; q < 4; ++q) {
        int i = t + q * 256;
        if (i < 960) orow[i] = f2bf(v[q] * invS);
    }
}

// ---------------------------------------------------------------------------

extern "C" void kernel_launch(void* const* d_in, const int* in_sizes, int n_in,
                              void* d_out, int out_size, void* d_ws, size_t ws_size,
                              hipStream_t stream)
{
    const float* emb[4]  = {(const float*)d_in[0], (const float*)d_in[1],
                            (const float*)d_in[2], (const float*)d_in[3]};
    const float* emb_all = (const float*)d_in[4];
    const float* w_mh[4] = {(const float*)d_in[5], (const float*)d_in[6],
                            (const float*)d_in[7], (const float*)d_in[8]};
    const float* w_mq = (const float*)d_in[9];
    const float* w_mk = (const float*)d_in[10];
    const float* w_mv = (const float*)d_in[11];
    const float* w_q[4] = {(const float*)d_in[12], (const float*)d_in[13],
                           (const float*)d_in[14], (const float*)d_in[15]};
    const float* w_qc = (const float*)d_in[16];
    const float* w_kc = (const float*)d_in[17];
    const float* w_vc = (const float*)d_in[18];
    const float* w_proj[4] = {(const float*)d_in[19], (const float*)d_in[20],
                              (const float*)d_in[21], (const float*)d_in[22]};
    float* out = (float*)d_out;

    // ---- arena (element offsets into ushort_t* U) ----
    ushort_t* U = (ushort_t*)d_ws;
    const long eWQKV = 0;          // 2,764,800  (WQ|WK|WV, k-contig rows)
    const long eWMH  = 2764800;    // 348,160
    const long eWPJ  = 3112960;    // 348,160
    const long eR1   = 3461120;    // embT_all -> Vc -> ctx       (7,864,320)
    const long eR2   = 11325440;   // embT_i  -> VcT -> ctxT      (7,864,320)
    const long eR3   = 19189760;   // Xqkv (23,592,960) -> S6 f32(15,728,640 us) + Pc -> oT
    const long ePc   = 34918400;   // Pc (7,372,800) ends 42,291,200
    const long eR4   = 42782720;   // mh_x -> P_all               (8,388,608)
    const long eQc   = 51171328;   // Qc (7,864,320)
    const long eKc   = 59035648;   // Kc (7,864,320)
    const long eQall = 66899968;   // q_all (8,388,608) ends 75,288,576
    float2* part  = (float2*)(U + 75288576);

    ushort_t* WQKVb = U + eWQKV;
    ushort_t* WMHb  = U + eWMH;
    ushort_t* WPJb  = U + eWPJ;
    ushort_t* embT_all = U + eR1;
    ushort_t* Vc    = U + eR1;
    ushort_t* ctx   = U + eR1;
    ushort_t* VcT   = U + eR2;
    ushort_t* ctxT  = U + eR2;
    ushort_t* Xqkv  = U + eR3;
    float*    S6    = (float*)(U + eR3);
    ushort_t* oT    = U + eR3;
    ushort_t* Pc    = U + ePc;
    ushort_t* mh_x  = U + eR4;
    ushort_t* P_all = U + eR4;
    ushort_t* QcB   = U + eQc;
    ushort_t* KcB   = U + eKc;
    ushort_t* q_all = U + eQall;
    ushort_t* embT_i[4] = {U + eR2, U + eR2 + 524288, U + eR2 + 1572864, U + eR2 + 3670016};

    const float scale = 0.0322748612183951400f;   // 1/sqrt(960)
    const long SB = (long)KVC * HWN;              // 983040
    const long S1024 = 1024L * 1024;
    const int CH[4] = {64, 128, 256, 512};
    const int mhoff[4] = {0, 4096, 20480, 86016};
    const int rowOff[4] = {0, 128, 256, 512};
    const long outOff[4] = {0, 524288, 1572864, 3670016};
    dim3 blk(256);
    dim3 blk512(512);

    // ---- f2b weights (plain) ----
    {
        F2BTab tf;
        const float* fs[11] = {w_mq, w_mk, w_mv, w_mh[0], w_mh[1], w_mh[2], w_mh[3],
                               w_proj[0], w_proj[1], w_proj[2], w_proj[3]};
        long fd[11] = {eWQKV, eWQKV + 921600, eWQKV + 1843200,
                       eWMH + 0, eWMH + 4096, eWMH + 20480, eWMH + 86016,
                       eWPJ + 0, eWPJ + 4096, eWPJ + 20480, eWPJ + 86016};
        int fn[11] = {900, 900, 900, 4, 16, 64, 256, 4, 16, 64, 256};
        int ftot = 0;
        for (int i = 0; i < 11; ++i) { tf.src[i] = fs[i]; tf.dstOff[i] = fd[i]; tf.nblk[i] = fn[i]; ftot += fn[i]; }
        tf.nseg = 11;
        f2b_batched<<<ftot, blk, 0, stream>>>(tf, U);
    }
    // ---- f2bT embeddings (transpose-convert) ----
    {
        F2TTab tt;
        const float* ts[5] = {emb_all, emb[0], emb[1], emb[2], emb[3]};
        long td[5] = {eR1, eR2, eR2 + 524288, eR2 + 1572864, eR2 + 3670016};
        int tR[5] = {960, 64, 128, 256, 512};
        int tn[5];
        long tsi[5], tso[5];
        int ttot = 0;
        for (int i = 0; i < 5; ++i) {
            tsi[i] = (long)tR[i] * 1024; tso[i] = tsi[i];
            tn[i] = NB * (tR[i] / 64) * 16; ttot += tn[i];
            tt.src[i] = ts[i]; tt.dstOff[i] = td[i]; tt.R[i] = tR[i];
            tt.sIn[i] = tsi[i]; tt.sOut[i] = tso[i]; tt.nblk[i] = tn[i];
        }
        tt.nseg = 5;
        f2bt_batched<<<ttot, blk, 0, stream>>>(tt, U);
    }

    auto nt1 = [&](const ushort_t* A, long sA, const ushort_t* B, long sB, long ldb,
                   void* C, long sC, int M, int K, int obf) {
        NTTab tb;
        for (int s = 0; s < 5; ++s) {
            tb.A[s] = A; tb.B[s] = B; tb.C[s] = C;
            tb.sA[s] = sA; tb.sB[s] = sB; tb.sC[s] = sC; tb.ldb[s] = ldb;
            tb.M[s] = M; tb.K[s] = K; tb.obf[s] = obf; tb.mt0[s] = (s == 0) ? 0 : (1 << 30);
        }
        tb.nseg = 1;
        dim3 g(NB, 8, (M + 127) / 128);
        mfma_gemm_nt_tab<<<g, blk512, 0, stream>>>(tb);
    };

    // ---- stage 1: QKV (M=2880) + 4x mhead conv1x1, one NT launch ----
    {
        NTTab tb;
        tb.A[0] = WQKVb; tb.B[0] = embT_all; tb.C[0] = Xqkv;
        tb.sA[0] = 0; tb.sB[0] = SB; tb.sC[0] = 2880L * 1024; tb.ldb[0] = 960;
        tb.M[0] = 2880; tb.K[0] = 960; tb.obf[0] = 1; tb.mt0[0] = 0;
        int mt = 23;
        for (int i = 0; i < 4; ++i) {
            tb.A[1 + i] = WMHb + mhoff[i]; tb.B[1 + i] = embT_i[i];
            tb.C[1 + i] = mh_x + (long)rowOff[i] * 1024;
            tb.sA[1 + i] = 0; tb.sB[1 + i] = (long)CH[i] * 1024; tb.sC[1 + i] = S1024;
            tb.ldb[1 + i] = CH[i];
            tb.M[1 + i] = CH[i]; tb.K[1 + i] = CH[i]; tb.obf[1 + i] = 1; tb.mt0[1 + i] = mt;
            mt += (CH[i] + 127) / 128;
        }
        tb.nseg = 5;
        dim3 g(NB, 8, mt);   // (8, 8, 31): x = batch -> XCD, y = N-tile inner
        mfma_gemm_nt_tab<<<g, blk512, 0, stream>>>(tb);
    }

    // ---- stencils: dw(Q,K,V) + gconv, one launch ----
    stencil_all<<<31232, blk, 0, stream>>>(Xqkv, mh_x, w_qc, w_kc, w_vc,
                                           w_q[0], w_q[1], w_q[2], w_q[3],
                                           QcB, KcB, Vc, q_all);

    // ---- Vc -> VcT ----
    trb_kernel<<<dim3(16, 15, NB), blk, 0, stream>>>(Vc, VcT);

    // ---- sim = Qc @ Kc^T * scale + stats ----
    mfma_gemm_nt_stats<<<dim3(NB, 8, 8), blk512, 0, stream>>>(
        QcB, KcB, S6, part, KVC, KVC, HWN, SB, SB, (long)KVC * KVC, scale);
    instnorm_softmax_bf16<<<NB * KVC, blk, 0, stream>>>(S6, Pc, part, KVC,
                                                        1.f / ((float)KVC * (float)KVC));

    // ---- ctx = NT(Pc, VcT) -> [960][1024] bf16 ----
    nt1(Pc, (long)KVC * KVC, VcT, SB, 960, ctx, SB, KVC, KVC, 1);

    // ---- ctx -> ctxT ----
    trb_kernel<<<dim3(16, 15, NB), blk, 0, stream>>>(ctx, ctxT);

    // ---- attn = q_all @ ctx^T * scale + stats ----
    mfma_gemm_nt_stats<<<dim3(NB, 8, 8), blk512, 0, stream>>>(
        q_all, ctx, S6, part, 1024, KVC, HWN, S1024, SB, SB, scale);
    softmax_attn_kernel<<<NB * 1024, blk, 0, stream>>>(S6, P_all, part);

    // ---- oT = NT(ctxT, P_all) -> [1024 hw][1024 ch] bf16 ----
    nt1(ctxT, SB, P_all, SB, 960, oT, S1024, 1024, KVC, 1);

    // ---- proj: 4 branches, one NT table launch (f32 out) ----
    {
        NTTab tb;
        int mt = 0;
        for (int i = 0; i < 4; ++i) {
            tb.A[i] = WPJb + mhoff[i]; tb.B[i] = oT + rowOff[i];
            tb.C[i] = out + outOff[i];
            tb.sA[i] = 0; tb.sB[i] = S1024; tb.sC[i] = (long)CH[i] * 1024;
            tb.ldb[i] = 1024;
            tb.M[i] = CH[i]; tb.K[i] = CH[i]; tb.obf[i] = 0; tb.mt0[i] = mt;
            mt += (CH[i] + 127) / 128;
        }
        tb.A[4] = tb.A[3]; tb.B[4] = tb.B[3]; tb.C[4] = tb.C[3];
        tb.sA[4] = 0; tb.sB[4] = 0; tb.sC[4] = 0; tb.ldb[4] = 1024;
        tb.M[4] = 1; tb.K[4] = 64; tb.obf[4] = 0; tb.mt0[4] = 1 << 30;
        tb.nseg = 4;
        dim3 g(NB, 8, mt);   // (8, 8, 8)
        mfma_gemm_nt_tab<<<g, blk512, 0, stream>>>(tb);
    }

    (void)in_sizes; (void)n_in; (void)out_size; (void)ws_size;
}